// Round 4
// baseline (242.799 us; speedup 1.0000x reference)
//
#include <hip/hip_runtime.h>

#define HW 192
#define DD 512
#define GG 64
#define PP 64
#define SLAB 98304  // 192*512 i8 bytes per slab

typedef __attribute__((ext_vector_type(4))) int intx4;
typedef __attribute__((ext_vector_type(16))) int intx16;

__device__ __forceinline__ unsigned int pk4(float a, float b, float c, float d) {
  int qa = (int)rintf(a), qb = (int)rintf(b), qc = (int)rintf(c), qd = (int)rintf(d);
  return (unsigned)(qa & 255) | ((unsigned)(qb & 255) << 8) |
         ((unsigned)(qc & 255) << 16) | ((unsigned)(qd & 255) << 24);
}

// L2-normalize over channels -> int8 (q = rint(127*v)), fragment-linear ws
// for mfma_i32_32x32x32_i8 (R14):
//   ws[slab][kslice S(16)][rowtile rt(6)][lane(64)][16B]
//   row/pos = rt*32 + (lane&31), channel k = S*32 + (lane>>5)*16 + byte.
// Direct analogy of the HW-validated 16x16x64 i8 layout (row=l&15,
// k=(l>>4)*16+e) that R8-R13 passed with. 1KB contiguous per frag =
// global_load_lds-friendly (wave-uniform dest + lane*16).
__global__ __launch_bounds__(512, 2) void norm_kernel(
    const float* __restrict__ gal, const float* __restrict__ prob,
    unsigned char* __restrict__ ws) {
  int b = blockIdx.x;  // 0..1535
  int s = b / 12;      // slab 0..127
  int q = b - s * 12;  // pos chunk 0..11 (16 positions)
  const float* in = (s < GG) ? (gal + (size_t)s * DD * HW)
                             : (prob + (size_t)(s - GG) * DD * HW);
  unsigned char* out = ws + (size_t)s * SLAB;
  int pos0 = q * 16;
  int t = threadIdx.x;

  __shared__ float T[16][524];   // 33.5 KB, [pos][c]
  __shared__ float sqa[128][17];
  __shared__ float sq2[16][17];
  __shared__ float scl[16];

  {
    int cq = t >> 2;   // 0..127
    int quad = t & 3;  // 0..3
    float p0 = 0.f, p1 = 0.f, p2 = 0.f, p3 = 0.f;
#pragma unroll
    for (int cb = 0; cb < 4; ++cb) {
      int c = cb * 128 + cq;
      const float4 v = *(const float4*)(in + (size_t)c * HW + pos0 + quad * 4);
      T[quad * 4 + 0][c] = v.x;
      T[quad * 4 + 1][c] = v.y;
      T[quad * 4 + 2][c] = v.z;
      T[quad * 4 + 3][c] = v.w;
      p0 += v.x * v.x; p1 += v.y * v.y; p2 += v.z * v.z; p3 += v.w * v.w;
    }
    sqa[cq][quad * 4 + 0] = p0;
    sqa[cq][quad * 4 + 1] = p1;
    sqa[cq][quad * 4 + 2] = p2;
    sqa[cq][quad * 4 + 3] = p3;
  }
  __syncthreads();
  if (t < 256) {
    int g2 = t >> 4, pos = t & 15;
    float v = 0.f;
#pragma unroll
    for (int r = 0; r < 8; ++r) v += sqa[g2 * 8 + r][pos];
    sq2[g2][pos] = v;
  }
  __syncthreads();
  if (t < 16) {
    float v = 0.f;
#pragma unroll
    for (int r = 0; r < 16; ++r) v += sq2[r][t];
    scl[t] = 1.f / fmaxf(sqrtf(v), 1e-12f);
  }
  __syncthreads();

  {
    // thread (p15, m): pos = q*16+p15, channels c = m*16 .. m*16+15.
    // frag coords: S = m>>1, rt = q>>1,
    //   frag-lane l = p15 + (q&1)*16 + (m&1)*32  (row = l&31, khalf = l>>5)
    int p15 = t & 15;
    int m = t >> 4;  // 0..31
    float sc = scl[p15] * 127.f;
    int base = m * 16;
    const float4 r0 = *(const float4*)&T[p15][base + 0];
    const float4 r1 = *(const float4*)&T[p15][base + 4];
    const float4 r2 = *(const float4*)&T[p15][base + 8];
    const float4 r3 = *(const float4*)&T[p15][base + 12];
    uint4 u;
    u.x = pk4(r0.x * sc, r0.y * sc, r0.z * sc, r0.w * sc);
    u.y = pk4(r1.x * sc, r1.y * sc, r1.z * sc, r1.w * sc);
    u.z = pk4(r2.x * sc, r2.y * sc, r2.z * sc, r2.w * sc);
    u.w = pk4(r3.x * sc, r3.y * sc, r3.z * sc, r3.w * sc);
    int S = m >> 1;
    int rt = q >> 1;
    int fl = p15 + ((q & 1) << 4) + ((m & 1) << 5);
    *(uint4*)(out + (size_t)S * 6144 + (size_t)rt * 1024 + (size_t)fl * 16) = u;
  }
}

// R14: 32x32x32 i8 MFMA (was 16x16x64). Diagnosis: R11/R12/R13 all show
// matrix-busy ~32us vs ~100us wall with NO bandwidth limit binding (per-CU
// totals: MFMA 39us, VMEM 41us, DS ~30us, L2 well under ceiling) -> the
// stall is wave-level MFMA issue coverage at ~2 waves/SIMD. 16x16 shapes
// need 1 MFMA issued per ~20cy/wave; every >=60%-MfmaUtil kernel on gfx950
// (m201/HK/AITER/hipBLASLt) uses 32x32. Switch halves instruction count
// (18/kb/wave @ ~36.6cy each) and is +12% rate (4404 vs 3944 TOPS).
// Operand regs halve too (48 vs 96: two 6-frag k-slice sets), ~210
// unified/wave -> firm 2 waves/SIMD.
// K-loop: 4-slot ring of 12KB k-slices (48KB LDS). Iter kb:
//   bar; STAGE(S=2kb+3 -> slot(S&3), S=2kb+4); DSRD(2kb+1 -> set1);
//   MFMA(set0 = slice 2kb); DSRD(2kb+2 -> set0); MFMA(set1)
// Slots touched per iter {2kb,2kb+1,2kb+2,2kb+3}&3 are all distinct ->
// one barrier/iter is WAR/RAW-safe (stages drained by next bar; reads
// drained by bar's implicit lgkmcnt(0)). Fully unrolled (rule #20).
#define GLOAD_LDS16(gp, lp)                                              \
  __builtin_amdgcn_global_load_lds(                                      \
      (const __attribute__((address_space(1))) unsigned int*)(gp),       \
      (__attribute__((address_space(3))) unsigned int*)(lp), 16, 0, 0)

__global__ __launch_bounds__(256, 2) void qaconv_gemm(
    const unsigned char* __restrict__ ws, const float* __restrict__ fcw,
    const float* __restrict__ bnw, const float* __restrict__ bnb,
    const float* __restrict__ bnm, const float* __restrict__ bnv,
    const float* __restrict__ fcb, const float* __restrict__ lw,
    const float* __restrict__ lb, const float* __restrict__ lm,
    const float* __restrict__ lv, float* __restrict__ out) {
  int bid0 = blockIdx.x;
  int bid = ((bid0 & 7) << 9) + (bid0 >> 3);  // XCD-contiguous supertiles
  int sb = bid >> 6, li = bid & 63;           // 8x8 supertiles
  int g = ((sb >> 3) << 3) + (li >> 3);
  int p = ((sb & 7) << 3) + (li & 7);
  const unsigned char* Bsrc = ws + (size_t)g * SLAB;         // galt[g]
  const unsigned char* Asrc = ws + (size_t)(GG + p) * SLAB;  // kern[p]

  // ring of 4 k-slice slots; slot: [A|B half 6144][rt 0..5][lane*16]
  __shared__ unsigned char sbuf[4][12288];  // 48 KB

  int tid = threadIdx.x;
  int lane = tid & 63;
  int wave = tid >> 6;
  int wi = wave >> 1, wj = wave & 1;

  intx16 acc[3][3];
#pragma unroll
  for (int a = 0; a < 3; ++a)
#pragma unroll
    for (int c = 0; c < 3; ++c)
#pragma unroll
      for (int r = 0; r < 16; ++r) acc[a][c][r] = 0;

  // staging: wave w -> (slice sidx = w>>1 of the 2 staged/iter, ab = w&1)
  int sab = wave & 1;    // 0 = A (kern), 1 = B (gal)
  int sidx = wave >> 1;  // 0 or 1
  const unsigned char* stgbase =
      (sab ? Bsrc : Asrc) + (size_t)lane * 16;

#define STAGE_SLICE(S)                                                    \
  do {                                                                    \
    const unsigned char* s_ = stgbase + (size_t)(S)*6144;                 \
    _Pragma("unroll") for (int r_ = 0; r_ < 6; ++r_) {                    \
      GLOAD_LDS16(s_ + r_ * 1024,                                         \
                  &sbuf[(S) & 3][sab * 6144 + r_ * 1024]);                \
    }                                                                     \
  } while (0)

#define DSRD(S, AX, BX)                                                   \
  do {                                                                    \
    const unsigned char* c_ = &sbuf[(S) & 3][lane * 16];                  \
    _Pragma("unroll") for (int i_ = 0; i_ < 3; ++i_) {                    \
      AX[i_] = *(const intx4*)(c_ + (wi * 3 + i_) * 1024);                \
      BX[i_] = *(const intx4*)(c_ + 6144 + (wj * 3 + i_) * 1024);         \
    }                                                                     \
  } while (0)

#define MFMA9(AX, BX)                                                     \
  do {                                                                    \
    _Pragma("unroll") for (int tj_ = 0; tj_ < 3; ++tj_) {                 \
      intx4 bb = BX[tj_];                                                 \
      _Pragma("unroll") for (int ti_ = 0; ti_ < 3; ++ti_)                 \
          acc[ti_][tj_] = __builtin_amdgcn_mfma_i32_32x32x32_i8(          \
              AX[ti_], bb, acc[ti_][tj_], 0, 0, 0);                       \
    }                                                                     \
  } while (0)

  intx4 a0[3], b0[3], a1[3], b1[3];

  // prologue: stage slices 0,1 (sidx split) + 2 (sidx0 pair)
  {
    int S = sidx;
    STAGE_SLICE(S);
  }
  if (sidx == 0) STAGE_SLICE(2);
  __syncthreads();  // vmcnt(0): slices 0..2 staged
  DSRD(0, a0, b0);

#pragma unroll
  for (int kb = 0; kb < 8; ++kb) {
    __syncthreads();
    {
      int S = 2 * kb + 3 + sidx;
      if (S <= 15) STAGE_SLICE(S);
    }
    DSRD(2 * kb + 1, a1, b1);
    MFMA9(a0, b0);  // slice 2kb
    if (kb < 7) DSRD(2 * kb + 2, a0, b0);
    MFMA9(a1, b1);  // slice 2kb+1
  }
#undef STAGE_SLICE
#undef DSRD
#undef MFMA9

  __syncthreads();  // all ds_reads done; safe to alias sbuf for epilogue

  float (*colpart)[HW] = (float (*)[HW]) & sbuf[0][0];     // [2][192]
  float (*rowpart)[HW] = (float (*)[HW]) & sbuf[0][1536];  // [2][192]
  float (*redbuf)[2] = (float (*)[2]) & sbuf[0][3072];     // [4][2]

  // ---- epilogue: dual max-pool in int32 ----
  // 32x32 C/D layout (m74/m101, dtype-independent):
  //   j = wj*96 + tj*32 + (lane&31)
  //   i = wi*96 + ti*32 + (r&3) + 8*(r>>2) + 4*(lane>>5)
  const float inv = 1.f / 16129.f;  // 1/127^2
  int cm[3];
  int rm[3][16];
#pragma unroll
  for (int tj = 0; tj < 3; ++tj) cm[tj] = -2147483647;
#pragma unroll
  for (int ti = 0; ti < 3; ++ti)
#pragma unroll
    for (int r = 0; r < 16; ++r) rm[ti][r] = -2147483647;
#pragma unroll
  for (int ti = 0; ti < 3; ++ti)
#pragma unroll
    for (int tj = 0; tj < 3; ++tj)
#pragma unroll
      for (int r = 0; r < 16; ++r) {
        int v = acc[ti][tj][r];
        cm[tj] = max(cm[tj], v);
        rm[ti][r] = max(rm[ti][r], v);
      }

#pragma unroll
  for (int tj = 0; tj < 3; ++tj) {
    int v = cm[tj];
    v = max(v, __shfl_xor(v, 32, 64));
    if (lane < 32) colpart[wi][wj * 96 + tj * 32 + lane] = (float)v * inv;
  }
#pragma unroll
  for (int ti = 0; ti < 3; ++ti)
#pragma unroll
    for (int r = 0; r < 16; ++r) {
      int v = rm[ti][r];
      v = max(v, __shfl_xor(v, 1, 64));
      v = max(v, __shfl_xor(v, 2, 64));
      v = max(v, __shfl_xor(v, 4, 64));
      v = max(v, __shfl_xor(v, 8, 64));
      v = max(v, __shfl_xor(v, 16, 64));
      if ((lane & 31) == 0)
        rowpart[wj][wi * 96 + ti * 32 + (r & 3) + 8 * (r >> 2) +
                    4 * (lane >> 5)] = (float)v * inv;
    }
  __syncthreads();

  // ---- fused BN -> fc -> lbn -> sigmoid ----
  float part = 0.f, wpart = 0.f;
  if (tid < HW) {
    float cmax = fmaxf(colpart[0][tid], colpart[1][tid]);  // score[j]
    float rmax = fmaxf(rowpart[0][tid], rowpart[1][tid]);  // score[192+i]
    float w1 = fcw[tid], w2 = fcw[HW + tid];
    part = cmax * w1 + rmax * w2;
    wpart = w1 + w2;
  }
#pragma unroll
  for (int off = 32; off > 0; off >>= 1) {
    part += __shfl_down(part, off, 64);
    wpart += __shfl_down(wpart, off, 64);
  }
  if (lane == 0) { redbuf[wave][0] = part; redbuf[wave][1] = wpart; }
  __syncthreads();
  if (tid == 0) {
    float s = redbuf[0][0] + redbuf[1][0] + redbuf[2][0] + redbuf[3][0];
    float wsum = redbuf[0][1] + redbuf[1][1] + redbuf[2][1] + redbuf[3][1];
    float bnA = bnw[0] * rsqrtf(bnv[0] + 1e-5f);
    float bnB = bnb[0] - bnm[0] * bnA;
    float sc = bnA * s + bnB * wsum + fcb[0];
    float lA = lw[0] * rsqrtf(lv[0] + 1e-5f);
    sc = (sc - lm[0]) * lA + lb[0];
    out[g * PP + p] = 1.f / (1.f + __expf(-sc * 0.1f));
  }
}

extern "C" void kernel_launch(void* const* d_in, const int* in_sizes, int n_in,
                              void* d_out, int out_size, void* d_ws, size_t ws_size,
                              hipStream_t stream) {
  const float* gal  = (const float*)d_in[0];
  const float* prob = (const float*)d_in[1];
  const float* bnw  = (const float*)d_in[2];
  const float* bnb  = (const float*)d_in[3];
  const float* bnm  = (const float*)d_in[4];
  const float* bnv  = (const float*)d_in[5];
  const float* fcw  = (const float*)d_in[6];
  const float* fcb  = (const float*)d_in[7];
  const float* lw   = (const float*)d_in[8];
  const float* lb   = (const float*)d_in[9];
  const float* lm   = (const float*)d_in[10];
  const float* lv   = (const float*)d_in[11];
  unsigned char* ws = (unsigned char*)d_ws;
  float* out = (float*)d_out;

  hipLaunchKernelGGL(norm_kernel, dim3(1536), dim3(512), 0, stream, gal, prob, ws);
  hipLaunchKernelGGL(qaconv_gemm, dim3(GG * PP), dim3(256), 0, stream, ws, fcw,
                     bnw, bnb, bnm, bnv, fcb, lw, lb, lm, lv, out);
}

// Round 5
// 211.957 us; speedup vs baseline: 1.1455x; 1.1455x over previous
//
#include <hip/hip_runtime.h>

#define HW 192
#define DD 512
#define GG 64
#define PP 64
#define SLAB 98304  // 192*512 i8 bytes per slab

typedef __attribute__((ext_vector_type(4))) int intx4;

__device__ __forceinline__ unsigned int pk4(float a, float b, float c, float d) {
  int qa = (int)rintf(a), qb = (int)rintf(b), qc = (int)rintf(c), qd = (int)rintf(d);
  return (unsigned)(qa & 255) | ((unsigned)(qb & 255) << 8) |
         ((unsigned)(qc & 255) << 16) | ((unsigned)(qd & 255) << 24);
}

// L2-normalize over channels -> int8 (q = rint(127*v)), fragment-linear ws:
// ws[slab][kb2(8)][R(12)][lane(64)][16B]
//   pos = R*16 + (lane&15), bytes = channels kb2*64 + (lane>>4)*16 .. +15.
// Per-lane operand order of mfma_i32_16x16x64_i8 (16B/lane, k = quad*16+j),
// so the GEMM stages fragments straight from global (1KB contiguous per
// frag = one global_load_lds_dwordx4 per wave). R13-proven layout.
__global__ __launch_bounds__(512, 2) void norm_kernel(
    const float* __restrict__ gal, const float* __restrict__ prob,
    unsigned char* __restrict__ ws) {
  int b = blockIdx.x;  // 0..1535
  int s = b / 12;      // slab 0..127
  int q = b - s * 12;  // pos chunk (= R) 0..11
  const float* in = (s < GG) ? (gal + (size_t)s * DD * HW)
                             : (prob + (size_t)(s - GG) * DD * HW);
  unsigned char* out = ws + (size_t)s * SLAB;
  int pos0 = q * 16;
  int t = threadIdx.x;

  __shared__ float T[16][524];   // 33.5 KB, [pos][c]
  __shared__ float sqa[128][17];
  __shared__ float sq2[16][17];
  __shared__ float scl[16];

  {
    int cq = t >> 2;   // 0..127
    int quad = t & 3;  // 0..3
    float p0 = 0.f, p1 = 0.f, p2 = 0.f, p3 = 0.f;
#pragma unroll
    for (int cb = 0; cb < 4; ++cb) {
      int c = cb * 128 + cq;
      const float4 v = *(const float4*)(in + (size_t)c * HW + pos0 + quad * 4);
      T[quad * 4 + 0][c] = v.x;
      T[quad * 4 + 1][c] = v.y;
      T[quad * 4 + 2][c] = v.z;
      T[quad * 4 + 3][c] = v.w;
      p0 += v.x * v.x; p1 += v.y * v.y; p2 += v.z * v.z; p3 += v.w * v.w;
    }
    sqa[cq][quad * 4 + 0] = p0;
    sqa[cq][quad * 4 + 1] = p1;
    sqa[cq][quad * 4 + 2] = p2;
    sqa[cq][quad * 4 + 3] = p3;
  }
  __syncthreads();
  if (t < 256) {
    int g2 = t >> 4, pos = t & 15;
    float v = 0.f;
#pragma unroll
    for (int r = 0; r < 8; ++r) v += sqa[g2 * 8 + r][pos];
    sq2[g2][pos] = v;
  }
  __syncthreads();
  if (t < 16) {
    float v = 0.f;
#pragma unroll
    for (int r = 0; r < 16; ++r) v += sq2[r][t];
    scl[t] = 1.f / fmaxf(sqrtf(v), 1e-12f);
  }
  __syncthreads();

  {
    int kb2 = t >> 6;    // 0..7 (uniform per wave)
    int lane = t & 63;
    int l4 = lane >> 4;  // k-quarter 0..3
    int pos = lane & 15; // 0..15
    float sc = scl[pos] * 127.f;
    int base = kb2 * 64 + l4 * 16;
    const float4 r0 = *(const float4*)&T[pos][base + 0];
    const float4 r1 = *(const float4*)&T[pos][base + 4];
    const float4 r2 = *(const float4*)&T[pos][base + 8];
    const float4 r3 = *(const float4*)&T[pos][base + 12];
    uint4 u;
    u.x = pk4(r0.x * sc, r0.y * sc, r0.z * sc, r0.w * sc);
    u.y = pk4(r1.x * sc, r1.y * sc, r1.z * sc, r1.w * sc);
    u.z = pk4(r2.x * sc, r2.y * sc, r2.z * sc, r2.w * sc);
    u.w = pk4(r3.x * sc, r3.y * sc, r3.z * sc, r3.w * sc);
    *(uint4*)(out + (size_t)kb2 * 12288 + (size_t)q * 1024 + (size_t)lane * 16) = u;
  }
}

// R15: T3+T4+T5 schedule (counted vmcnt, raw s_barrier, setprio) on R13's
// layout. Post-mortems R11-R14: matrix-busy ~32us in EVERY structure, no
// pipe near ceiling (MFMA 37.6us, VMEM-dedup 20us, DS ~30us per CU), and
// MfmaUtil pinned at the documented ~36% ceiling of 2-barrier K-loops whose
// __syncthreads emits s_waitcnt vmcnt(0) lgkmcnt(0) (full drain) each step.
// R14 falsified the issue-rate theory (fewer instructions -> worse). The
// guide's isolated lever for exactly this plateau is counted-vmcnt phase
// scheduling (m218: +38-73%), setprio paying only on phase-split (m218b).
// m201 proves 62% MfmaUtil at 2 waves/SIMD with 16x16 MFMA.
//
// Structure: 3-slot ring of 24KB tile-slots (72KB LDS, still 2 blocks/CU).
// PHASE(kb): s_waitcnt vmcnt(6) lgkmcnt(0); s_barrier;
//            STAGE(kb+3 -> slot (kb+3)%3); DSRD(kb+1 -> regs[(kb+1)&1]);
//            setprio(1); 36x MFMA(regs[kb&1]); setprio(0)
// Ledger (per wave, STAGE = 6 loads): at PHASE(kb) top, in-flight =
// {stage(kb+1), stage(kb+2)} = 12; vmcnt(6) retires exactly stage(kb+1)
// (issued 2 phases = ~3400cy earlier -> covers HBM miss) leaving stage(kb+2)
// IN FLIGHT across the MFMA phase (never drains to 0 until epilogue).
// Barrier publishes: all waves' stage(kb+1) landed -> DSRD(kb+1) RAW-safe.
// WAR: STAGE(kb+3) overwrites slot kb%3 = tile kb, whose ds_reads (issued
// PHASE(kb-1)) every wave retired via its lgkmcnt(0) before this barrier.
// Raw s_barrier adds no implicit waitcnt; all ring/reg indices are literal
// after full unroll (rule #20). Epilogue vmcnt(0)s hit >=2-phase-old loads.
#define GLOAD_LDS16(gp, lp)                                              \
  __builtin_amdgcn_global_load_lds(                                      \
      (const __attribute__((address_space(1))) unsigned int*)(gp),       \
      (__attribute__((address_space(3))) unsigned int*)(lp), 16, 0, 0)

__global__ __launch_bounds__(256, 2) void qaconv_gemm(
    const unsigned char* __restrict__ ws, const float* __restrict__ fcw,
    const float* __restrict__ bnw, const float* __restrict__ bnb,
    const float* __restrict__ bnm, const float* __restrict__ bnv,
    const float* __restrict__ fcb, const float* __restrict__ lw,
    const float* __restrict__ lb, const float* __restrict__ lm,
    const float* __restrict__ lv, float* __restrict__ out) {
  int bid0 = blockIdx.x;
  int bid = ((bid0 & 7) << 9) + (bid0 >> 3);  // XCD-contiguous supertiles
  int sb = bid >> 6, li = bid & 63;           // 8x8 supertiles
  int g = ((sb >> 3) << 3) + (li >> 3);
  int p = ((sb & 7) << 3) + (li & 7);
  const unsigned char* Bsrc = ws + (size_t)g * SLAB;         // galt[g] frags
  const unsigned char* Asrc = ws + (size_t)(GG + p) * SLAB;  // kern[p] frags

  // 3-slot ring; slot holds one K-tile: frag f (0..11 = A R0..11,
  // 12..23 = B R0..11) at f*1024 + lane*16.  3 x 24 KB = 72 KB.
  __shared__ unsigned char sbuf[3][24576];

  int tid = threadIdx.x;
  int lane = tid & 63;
  int wave = tid >> 6;
  int wi = wave >> 1, wj = wave & 1;
  int l15 = lane & 15, l4 = lane >> 4;

  intx4 acc[6][6];
#pragma unroll
  for (int a = 0; a < 6; ++a)
#pragma unroll
    for (int c = 0; c < 6; ++c) acc[a][c] = (intx4){0, 0, 0, 0};

  // staging: wave w owns frags w*6 .. w*6+5  (w<2 -> A rows, w>=2 -> B rows)
  const unsigned char* stgsrc =
      ((wave < 2) ? Asrc : Bsrc) + (size_t)((wave & 1) * 6) * 1024 +
      (size_t)lane * 16;
  int fbase = wave * 6;  // frag index base (uniform per wave)

#define STAGE(KB)                                                         \
  do {                                                                    \
    const unsigned char* s_ = stgsrc + (size_t)(KB)*12288;                \
    _Pragma("unroll") for (int i_ = 0; i_ < 6; ++i_) {                    \
      GLOAD_LDS16(s_ + i_ * 1024, &sbuf[(KB) % 3][(fbase + i_) * 1024]);  \
    }                                                                     \
  } while (0)

  // register double-buffer: rb = tile kb & 1
  intx4 aR[2][6], bR[2][6];

#define DSRD(KB, RB)                                                      \
  do {                                                                    \
    const unsigned char* cb_ = &sbuf[(KB) % 3][lane * 16];                \
    _Pragma("unroll") for (int i_ = 0; i_ < 6; ++i_) {                    \
      aR[RB][i_] = *(const intx4*)(cb_ + (wi * 6 + i_) * 1024);           \
      bR[RB][i_] = *(const intx4*)(cb_ + (12 + wj * 6 + i_) * 1024);      \
    }                                                                     \
  } while (0)

#define MFMAB(RB)                                                         \
  do {                                                                    \
    _Pragma("unroll") for (int jt_ = 0; jt_ < 6; ++jt_) {                 \
      intx4 bb = bR[RB][jt_];                                             \
      _Pragma("unroll") for (int it_ = 0; it_ < 6; ++it_)                 \
          acc[it_][jt_] = __builtin_amdgcn_mfma_i32_16x16x64_i8(          \
              aR[RB][it_], bb, acc[it_][jt_], 0, 0, 0);                   \
    }                                                                     \
  } while (0)

#define PHASE(KB, VMW)                                                    \
  do {                                                                    \
    asm volatile("s_waitcnt vmcnt(" #VMW ") lgkmcnt(0)" ::: "memory");    \
    __builtin_amdgcn_s_barrier();                                         \
    if ((KB) + 3 <= 7) STAGE((KB) + 3);                                   \
    if ((KB) + 1 <= 7) DSRD((KB) + 1, ((KB) + 1) & 1);                    \
    __builtin_amdgcn_s_setprio(1);                                        \
    MFMAB((KB)&1);                                                        \
    __builtin_amdgcn_s_setprio(0);                                        \
  } while (0)

  // prologue: fill 3 ring slots; publish tile 0; keep 12 loads in flight
  STAGE(0);
  STAGE(1);
  STAGE(2);
  asm volatile("s_waitcnt vmcnt(12)" ::: "memory");  // stage(0) landed
  __builtin_amdgcn_s_barrier();
  DSRD(0, 0);

  PHASE(0, 6);
  PHASE(1, 6);
  PHASE(2, 6);
  PHASE(3, 6);
  PHASE(4, 6);
  PHASE(5, 6);
  PHASE(6, 0);
  PHASE(7, 0);

#undef STAGE
#undef DSRD
#undef MFMAB
#undef PHASE

  __syncthreads();  // full drain; safe to alias sbuf for epilogue

  // epilogue scratch aliases the stage buffer
  float (*colpart)[HW] = (float (*)[HW]) & sbuf[0][0];      // [2][192]
  float (*rowpart)[HW] = (float (*)[HW]) & sbuf[0][1536];   // [2][192]
  float (*redbuf)[2] = (float (*)[2]) & sbuf[0][3072];      // [4][2]

  // ---- epilogue: dual max-pool in int32 ----
  // C/D layout: i = wi*96 + it*16 + l4*4 + r ; j = wj*96 + jt*16 + l15
  const float inv = 1.f / 16129.f;  // 1/127^2
  int cm[6];
  int rm[6][4];
#pragma unroll
  for (int jt = 0; jt < 6; ++jt) cm[jt] = -2147483647;
#pragma unroll
  for (int it = 0; it < 6; ++it)
#pragma unroll
    for (int r = 0; r < 4; ++r) rm[it][r] = -2147483647;
#pragma unroll
  for (int it = 0; it < 6; ++it)
#pragma unroll
    for (int jt = 0; jt < 6; ++jt)
#pragma unroll
      for (int r = 0; r < 4; ++r) {
        int v = acc[it][jt][r];
        cm[jt] = max(cm[jt], v);
        rm[it][r] = max(rm[it][r], v);
      }

#pragma unroll
  for (int jt = 0; jt < 6; ++jt) {
    int v = cm[jt];
    v = max(v, __shfl_xor(v, 16, 64));
    v = max(v, __shfl_xor(v, 32, 64));
    if (lane < 16) colpart[wi][wj * 96 + jt * 16 + lane] = (float)v * inv;
  }
#pragma unroll
  for (int it = 0; it < 6; ++it)
#pragma unroll
    for (int r = 0; r < 4; ++r) {
      int v = rm[it][r];
      v = max(v, __shfl_xor(v, 1, 64));
      v = max(v, __shfl_xor(v, 2, 64));
      v = max(v, __shfl_xor(v, 4, 64));
      v = max(v, __shfl_xor(v, 8, 64));
      if (l15 == 0) rowpart[wj][wi * 96 + it * 16 + l4 * 4 + r] = (float)v * inv;
    }
  __syncthreads();

  // ---- fused BN -> fc -> lbn -> sigmoid ----
  float part = 0.f, wpart = 0.f;
  if (tid < HW) {
    float cmax = fmaxf(colpart[0][tid], colpart[1][tid]);  // score[j]
    float rmax = fmaxf(rowpart[0][tid], rowpart[1][tid]);  // score[192+i]
    float w1 = fcw[tid], w2 = fcw[HW + tid];
    part = cmax * w1 + rmax * w2;
    wpart = w1 + w2;
  }
#pragma unroll
  for (int off = 32; off > 0; off >>= 1) {
    part += __shfl_down(part, off, 64);
    wpart += __shfl_down(wpart, off, 64);
  }
  if (lane == 0) { redbuf[wave][0] = part; redbuf[wave][1] = wpart; }
  __syncthreads();
  if (tid == 0) {
    float s = redbuf[0][0] + redbuf[1][0] + redbuf[2][0] + redbuf[3][0];
    float wsum = redbuf[0][1] + redbuf[1][1] + redbuf[2][1] + redbuf[3][1];
    float bnA = bnw[0] * rsqrtf(bnv[0] + 1e-5f);
    float bnB = bnb[0] - bnm[0] * bnA;
    float sc = bnA * s + bnB * wsum + fcb[0];
    float lA = lw[0] * rsqrtf(lv[0] + 1e-5f);
    sc = (sc - lm[0]) * lA + lb[0];
    out[g * PP + p] = 1.f / (1.f + __expf(-sc * 0.1f));
  }
}

extern "C" void kernel_launch(void* const* d_in, const int* in_sizes, int n_in,
                              void* d_out, int out_size, void* d_ws, size_t ws_size,
                              hipStream_t stream) {
  const float* gal  = (const float*)d_in[0];
  const float* prob = (const float*)d_in[1];
  const float* bnw  = (const float*)d_in[2];
  const float* bnb  = (const float*)d_in[3];
  const float* bnm  = (const float*)d_in[4];
  const float* bnv  = (const float*)d_in[5];
  const float* fcw  = (const float*)d_in[6];
  const float* fcb  = (const float*)d_in[7];
  const float* lw   = (const float*)d_in[8];
  const float* lb   = (const float*)d_in[9];
  const float* lm   = (const float*)d_in[10];
  const float* lv   = (const float*)d_in[11];
  unsigned char* ws = (unsigned char*)d_ws;
  float* out = (float*)d_out;

  hipLaunchKernelGGL(norm_kernel, dim3(1536), dim3(512), 0, stream, gal, prob, ws);
  hipLaunchKernelGGL(qaconv_gemm, dim3(GG * PP), dim3(256), 0, stream, ws, fcw,
                     bnw, bnb, bnm, bnv, fcb, lw, lb, lm, lv, out);
}

// Round 6
// 205.777 us; speedup vs baseline: 1.1799x; 1.0300x over previous
//
#include <hip/hip_runtime.h>

#define HW 192
#define DD 512
#define GG 64
#define PP 64
#define SLAB 98304  // 192*512 i8 bytes per slab

typedef __attribute__((ext_vector_type(4))) int intx4;

__device__ __forceinline__ unsigned int pk4(float a, float b, float c, float d) {
  int qa = (int)rintf(a), qb = (int)rintf(b), qc = (int)rintf(c), qd = (int)rintf(d);
  return (unsigned)(qa & 255) | ((unsigned)(qb & 255) << 8) |
         ((unsigned)(qc & 255) << 16) | ((unsigned)(qd & 255) << 24);
}

// L2-normalize over channels -> int8 (q = rint(127*v)), fragment-linear ws:
// ws[slab][kb2(8)][R(12)][lane(64)][16B]
//   pos = R*16 + (lane&15), bytes = channels kb2*64 + (lane>>4)*16 .. +15.
// Per-lane operand order of mfma_i32_16x16x64_i8 (16B/lane, k = quad*16+j).
// R13-proven layout, unchanged.
__global__ __launch_bounds__(512, 2) void norm_kernel(
    const float* __restrict__ gal, const float* __restrict__ prob,
    unsigned char* __restrict__ ws) {
  int b = blockIdx.x;  // 0..1535
  int s = b / 12;      // slab 0..127
  int q = b - s * 12;  // pos chunk (= R) 0..11
  const float* in = (s < GG) ? (gal + (size_t)s * DD * HW)
                             : (prob + (size_t)(s - GG) * DD * HW);
  unsigned char* out = ws + (size_t)s * SLAB;
  int pos0 = q * 16;
  int t = threadIdx.x;

  __shared__ float T[16][524];   // 33.5 KB, [pos][c]
  __shared__ float sqa[128][17];
  __shared__ float sq2[16][17];
  __shared__ float scl[16];

  {
    int cq = t >> 2;   // 0..127
    int quad = t & 3;  // 0..3
    float p0 = 0.f, p1 = 0.f, p2 = 0.f, p3 = 0.f;
#pragma unroll
    for (int cb = 0; cb < 4; ++cb) {
      int c = cb * 128 + cq;
      const float4 v = *(const float4*)(in + (size_t)c * HW + pos0 + quad * 4);
      T[quad * 4 + 0][c] = v.x;
      T[quad * 4 + 1][c] = v.y;
      T[quad * 4 + 2][c] = v.z;
      T[quad * 4 + 3][c] = v.w;
      p0 += v.x * v.x; p1 += v.y * v.y; p2 += v.z * v.z; p3 += v.w * v.w;
    }
    sqa[cq][quad * 4 + 0] = p0;
    sqa[cq][quad * 4 + 1] = p1;
    sqa[cq][quad * 4 + 2] = p2;
    sqa[cq][quad * 4 + 3] = p3;
  }
  __syncthreads();
  if (t < 256) {
    int g2 = t >> 4, pos = t & 15;
    float v = 0.f;
#pragma unroll
    for (int r = 0; r < 8; ++r) v += sqa[g2 * 8 + r][pos];
    sq2[g2][pos] = v;
  }
  __syncthreads();
  if (t < 16) {
    float v = 0.f;
#pragma unroll
    for (int r = 0; r < 16; ++r) v += sq2[r][t];
    scl[t] = 1.f / fmaxf(sqrtf(v), 1e-12f);
  }
  __syncthreads();

  {
    int kb2 = t >> 6;    // 0..7 (uniform per wave)
    int lane = t & 63;
    int l4 = lane >> 4;  // k-quarter 0..3
    int pos = lane & 15; // 0..15
    float sc = scl[pos] * 127.f;
    int base = kb2 * 64 + l4 * 16;
    const float4 r0 = *(const float4*)&T[pos][base + 0];
    const float4 r1 = *(const float4*)&T[pos][base + 4];
    const float4 r2 = *(const float4*)&T[pos][base + 8];
    const float4 r3 = *(const float4*)&T[pos][base + 12];
    uint4 u;
    u.x = pk4(r0.x * sc, r0.y * sc, r0.z * sc, r0.w * sc);
    u.y = pk4(r1.x * sc, r1.y * sc, r1.z * sc, r1.w * sc);
    u.z = pk4(r2.x * sc, r2.y * sc, r2.z * sc, r2.w * sc);
    u.w = pk4(r3.x * sc, r3.y * sc, r3.z * sc, r3.w * sc);
    *(uint4*)(out + (size_t)kb2 * 12288 + (size_t)q * 1024 + (size_t)lane * 16) = u;
  }
}

// R16: OCCUPANCY. R11-R15 falsified every schedule/delivery theory: five
// structures (barrier-free direct, barrier-staged, 3-stage pipe, 32x32
// shape, counted-vmcnt phases) all land wall 98-151us with matrix-busy
// ~32us and no pipe near ceiling. The one constant: 2 waves/SIMD (acc 144
// AGPR + 128 VGPR; Occupancy ~20%). The m16 i8 ceiling ran 8 waves/SIMD.
// At 2/SIMD, co-resident waves phase-lock and stall together (R11 had NO
// barriers and still 33% -> not schedule). Fix: halve the wave tile so 4
// waves/SIMD fit: 8 waves/block (2Wi x 4Wj), wave tile 96x48 -> acc 72 +
// operands 36 + addr ~15 < 128 regs (m69: <=128 -> 16 waves/CU).
// __launch_bounds__(512,4). LDS: 3-slot ring x 24KB = 72KB -> 2 blocks/CU.
// Schedule: proven counted-vmcnt, 2-tiles-ahead, single-buffered operands
// (per-wave ds->MFMA serialization now covered by 3 sibling waves = TLP).
// PHASE(kb): wait vmcnt(3) [entry in-flight {stage kb, kb+1}=6 -> retires
// stage(kb), keeps stage(kb+1) in flight]; s_barrier [publishes tile kb];
// STAGE(kb+2) [slot (kb+2)%3 = tile kb-1's slot: its ds_reads retired
// before each wave's MFMA(kb-1) issue, which precedes barrier arrival ->
// WAR-safe]; DSRD(kb); MFMA18(kb) [compiler inserts lgkm waits].
// Budget/phase/CU: MFMA 1469cy, DS 144KB~1730cy, VMEM 48KB=768cy.
#define GLOAD_LDS16(gp, lp)                                              \
  __builtin_amdgcn_global_load_lds(                                      \
      (const __attribute__((address_space(1))) unsigned int*)(gp),       \
      (__attribute__((address_space(3))) unsigned int*)(lp), 16, 0, 0)

__global__ __launch_bounds__(512, 4) void qaconv_gemm(
    const unsigned char* __restrict__ ws, const float* __restrict__ fcw,
    const float* __restrict__ bnw, const float* __restrict__ bnb,
    const float* __restrict__ bnm, const float* __restrict__ bnv,
    const float* __restrict__ fcb, const float* __restrict__ lw,
    const float* __restrict__ lb, const float* __restrict__ lm,
    const float* __restrict__ lv, float* __restrict__ out) {
  int bid0 = blockIdx.x;
  int bid = ((bid0 & 7) << 9) + (bid0 >> 3);  // XCD-contiguous supertiles
  int sb = bid >> 6, li = bid & 63;           // 8x8 supertiles
  int g = ((sb >> 3) << 3) + (li >> 3);
  int p = ((sb & 7) << 3) + (li & 7);
  const unsigned char* Bsrc = ws + (size_t)g * SLAB;         // galt[g] frags
  const unsigned char* Asrc = ws + (size_t)(GG + p) * SLAB;  // kern[p] frags

  // 3-slot ring; slot = one K-tile: frag f (0..11 = A rows, 12..23 = B rows)
  // at f*1024 + lane*16.  3 x 24 KB = 72 KB.
  __shared__ unsigned char sbuf[3][24576];

  int tid = threadIdx.x;
  int lane = tid & 63;
  int wave = tid >> 6;         // 0..7
  int wi = wave >> 2;          // 0..1  (M half: rows wi*96..)
  int wj = wave & 3;           // 0..3  (N quarter: cols wj*48..)
  int l15 = lane & 15, l4 = lane >> 4;

  intx4 acc[6][3];
#pragma unroll
  for (int a = 0; a < 6; ++a)
#pragma unroll
    for (int c = 0; c < 3; ++c) acc[a][c] = (intx4){0, 0, 0, 0};

  // staging: wave w owns frags 3w .. 3w+2  (w<4 -> A rows, w>=4 -> B rows)
  const unsigned char* stgsrc =
      ((wave < 4) ? (Asrc + (size_t)(wave * 3) * 1024)
                  : (Bsrc + (size_t)(wave * 3 - 12) * 1024)) +
      (size_t)lane * 16;
  int fbase = wave * 3;  // frag index base (uniform per wave)

#define STAGE(KB)                                                         \
  do {                                                                    \
    const unsigned char* s_ = stgsrc + (size_t)(KB)*12288;                \
    _Pragma("unroll") for (int i_ = 0; i_ < 3; ++i_) {                    \
      GLOAD_LDS16(s_ + i_ * 1024, &sbuf[(KB) % 3][(fbase + i_) * 1024]);  \
    }                                                                     \
  } while (0)

  intx4 a[6], b[3];

#define DSRD(KB)                                                          \
  do {                                                                    \
    const unsigned char* cb_ = &sbuf[(KB) % 3][lane * 16];                \
    _Pragma("unroll") for (int i_ = 0; i_ < 6; ++i_)                      \
        a[i_] = *(const intx4*)(cb_ + (wi * 6 + i_) * 1024);              \
    _Pragma("unroll") for (int j_ = 0; j_ < 3; ++j_)                      \
        b[j_] = *(const intx4*)(cb_ + (12 + wj * 3 + j_) * 1024);         \
  } while (0)

#define MFMA18()                                                          \
  do {                                                                    \
    _Pragma("unroll") for (int jt_ = 0; jt_ < 3; ++jt_) {                 \
      intx4 bb = b[jt_];                                                  \
      _Pragma("unroll") for (int it_ = 0; it_ < 6; ++it_)                 \
          acc[it_][jt_] = __builtin_amdgcn_mfma_i32_16x16x64_i8(          \
              a[it_], bb, acc[it_][jt_], 0, 0, 0);                        \
    }                                                                     \
  } while (0)

#define PHASE(KB, VMW)                                                    \
  do {                                                                    \
    asm volatile("s_waitcnt vmcnt(" #VMW ")" ::: "memory");               \
    __builtin_amdgcn_s_barrier();                                         \
    if ((KB) + 2 <= 7) STAGE((KB) + 2);                                   \
    DSRD(KB);                                                             \
    __builtin_amdgcn_s_setprio(1);                                        \
    MFMA18();                                                             \
    __builtin_amdgcn_s_setprio(0);                                        \
  } while (0)

  // prologue: 2 tiles in flight (6 loads/wave)
  STAGE(0);
  STAGE(1);

  PHASE(0, 3);
  PHASE(1, 3);
  PHASE(2, 3);
  PHASE(3, 3);
  PHASE(4, 3);
  PHASE(5, 3);
  PHASE(6, 3);
  PHASE(7, 0);

#undef STAGE
#undef DSRD
#undef MFMA18
#undef PHASE

  __syncthreads();  // all LDS reads done; safe to alias sbuf for epilogue

  // epilogue scratch aliases the ring buffer
  float (*colpart)[HW] = (float (*)[HW]) & sbuf[0][0];      // [2][192]
  float (*rowpart)[HW] = (float (*)[HW]) & sbuf[0][1536];   // [4][192]
  float (*redbuf)[2] = (float (*)[2]) & sbuf[0][4608];      // [8][2]

  // ---- epilogue: dual max-pool in int32 ----
  // C/D layout: i = wi*96 + it*16 + l4*4 + r ; j = wj*48 + jt*16 + l15
  const float inv = 1.f / 16129.f;  // 1/127^2
  int cm[3];
  int rm[6][4];
#pragma unroll
  for (int jt = 0; jt < 3; ++jt) cm[jt] = -2147483647;
#pragma unroll
  for (int it = 0; it < 6; ++it)
#pragma unroll
    for (int r = 0; r < 4; ++r) rm[it][r] = -2147483647;
#pragma unroll
  for (int it = 0; it < 6; ++it)
#pragma unroll
    for (int jt = 0; jt < 3; ++jt)
#pragma unroll
      for (int r = 0; r < 4; ++r) {
        int v = acc[it][jt][r];
        cm[jt] = max(cm[jt], v);
        rm[it][r] = max(rm[it][r], v);
      }

  // col-max over this wave's 96 rows: reduce across l4 (xor 16, 32)
#pragma unroll
  for (int jt = 0; jt < 3; ++jt) {
    int v = cm[jt];
    v = max(v, __shfl_xor(v, 16, 64));
    v = max(v, __shfl_xor(v, 32, 64));
    if (lane < 16) colpart[wi][wj * 48 + jt * 16 + lane] = (float)v * inv;
  }
  // row-max over this wave's 48 cols: reduce across l15 (xor 1,2,4,8)
#pragma unroll
  for (int it = 0; it < 6; ++it)
#pragma unroll
    for (int r = 0; r < 4; ++r) {
      int v = rm[it][r];
      v = max(v, __shfl_xor(v, 1, 64));
      v = max(v, __shfl_xor(v, 2, 64));
      v = max(v, __shfl_xor(v, 4, 64));
      v = max(v, __shfl_xor(v, 8, 64));
      if (l15 == 0)
        rowpart[wj][wi * 96 + it * 16 + l4 * 4 + r] = (float)v * inv;
    }
  __syncthreads();

  // ---- fused BN -> fc -> lbn -> sigmoid ----
  float part = 0.f, wpart = 0.f;
  if (tid < HW) {
    float cmax = fmaxf(colpart[0][tid], colpart[1][tid]);  // score[j]
    float rmax = fmaxf(fmaxf(rowpart[0][tid], rowpart[1][tid]),
                       fmaxf(rowpart[2][tid], rowpart[3][tid]));  // score[192+i]
    float w1 = fcw[tid], w2 = fcw[HW + tid];
    part = cmax * w1 + rmax * w2;
    wpart = w1 + w2;
  }
#pragma unroll
  for (int off = 32; off > 0; off >>= 1) {
    part += __shfl_down(part, off, 64);
    wpart += __shfl_down(wpart, off, 64);
  }
  if (lane == 0) { redbuf[wave][0] = part; redbuf[wave][1] = wpart; }
  __syncthreads();
  if (tid == 0) {
    float s = 0.f, wsum = 0.f;
#pragma unroll
    for (int w = 0; w < 8; ++w) { s += redbuf[w][0]; wsum += redbuf[w][1]; }
    float bnA = bnw[0] * rsqrtf(bnv[0] + 1e-5f);
    float bnB = bnb[0] - bnm[0] * bnA;
    float sc = bnA * s + bnB * wsum + fcb[0];
    float lA = lw[0] * rsqrtf(lv[0] + 1e-5f);
    sc = (sc - lm[0]) * lA + lb[0];
    out[g * PP + p] = 1.f / (1.f + __expf(-sc * 0.1f));
  }
}

extern "C" void kernel_launch(void* const* d_in, const int* in_sizes, int n_in,
                              void* d_out, int out_size, void* d_ws, size_t ws_size,
                              hipStream_t stream) {
  const float* gal  = (const float*)d_in[0];
  const float* prob = (const float*)d_in[1];
  const float* bnw  = (const float*)d_in[2];
  const float* bnb  = (const float*)d_in[3];
  const float* bnm  = (const float*)d_in[4];
  const float* bnv  = (const float*)d_in[5];
  const float* fcw  = (const float*)d_in[6];
  const float* fcb  = (const float*)d_in[7];
  const float* lw   = (const float*)d_in[8];
  const float* lb   = (const float*)d_in[9];
  const float* lm   = (const float*)d_in[10];
  const float* lv   = (const float*)d_in[11];
  unsigned char* ws = (unsigned char*)d_ws;
  float* out = (float*)d_out;

  hipLaunchKernelGGL(norm_kernel, dim3(1536), dim3(512), 0, stream, gal, prob, ws);
  hipLaunchKernelGGL(qaconv_gemm, dim3(GG * PP), dim3(512), 0, stream, ws, fcw,
                     bnw, bnb, bnm, bnv, fcb, lw, lb, lm, lv, out);
}

// Round 7
// 196.573 us; speedup vs baseline: 1.2352x; 1.0468x over previous
//
#include <hip/hip_runtime.h>

#define HW 192
#define DD 512
#define GG 64
#define PP 64
#define SLAB 98304  // 192*512 i8 bytes per slab

typedef __attribute__((ext_vector_type(4))) int intx4;

__device__ __forceinline__ unsigned int pk4(float a, float b, float c, float d) {
  int qa = (int)rintf(a), qb = (int)rintf(b), qc = (int)rintf(c), qd = (int)rintf(d);
  return (unsigned)(qa & 255) | ((unsigned)(qb & 255) << 8) |
         ((unsigned)(qc & 255) << 16) | ((unsigned)(qd & 255) << 24);
}

// L2-normalize over channels -> int8 (q = rint(127*v)), fragment-linear ws:
// ws[slab][kb2(8)][R(12)][lane(64)][16B]
//   pos = R*16 + (lane&15), bytes = channels kb2*64 + (lane>>4)*16 .. +15.
// Per-lane operand order of mfma_i32_16x16x64_i8 (16B/lane, k = quad*16+j).
// UNCHANGED this round (R17 is a gemm-only change): next round's top-5
// table splits the ~96us residual — if norm_kernel appears there, it's the
// residual and gets rewritten; if absent, residual is harness-side.
__global__ __launch_bounds__(512, 2) void norm_kernel(
    const float* __restrict__ gal, const float* __restrict__ prob,
    unsigned char* __restrict__ ws) {
  int b = blockIdx.x;  // 0..1535
  int s = b / 12;      // slab 0..127
  int q = b - s * 12;  // pos chunk (= R) 0..11
  const float* in = (s < GG) ? (gal + (size_t)s * DD * HW)
                             : (prob + (size_t)(s - GG) * DD * HW);
  unsigned char* out = ws + (size_t)s * SLAB;
  int pos0 = q * 16;
  int t = threadIdx.x;

  __shared__ float T[16][524];   // 33.5 KB, [pos][c]
  __shared__ float sqa[128][17];
  __shared__ float sq2[16][17];
  __shared__ float scl[16];

  {
    int cq = t >> 2;   // 0..127
    int quad = t & 3;  // 0..3
    float p0 = 0.f, p1 = 0.f, p2 = 0.f, p3 = 0.f;
#pragma unroll
    for (int cb = 0; cb < 4; ++cb) {
      int c = cb * 128 + cq;
      const float4 v = *(const float4*)(in + (size_t)c * HW + pos0 + quad * 4);
      T[quad * 4 + 0][c] = v.x;
      T[quad * 4 + 1][c] = v.y;
      T[quad * 4 + 2][c] = v.z;
      T[quad * 4 + 3][c] = v.w;
      p0 += v.x * v.x; p1 += v.y * v.y; p2 += v.z * v.z; p3 += v.w * v.w;
    }
    sqa[cq][quad * 4 + 0] = p0;
    sqa[cq][quad * 4 + 1] = p1;
    sqa[cq][quad * 4 + 2] = p2;
    sqa[cq][quad * 4 + 3] = p3;
  }
  __syncthreads();
  if (t < 256) {
    int g2 = t >> 4, pos = t & 15;
    float v = 0.f;
#pragma unroll
    for (int r = 0; r < 8; ++r) v += sqa[g2 * 8 + r][pos];
    sq2[g2][pos] = v;
  }
  __syncthreads();
  if (t < 16) {
    float v = 0.f;
#pragma unroll
    for (int r = 0; r < 16; ++r) v += sq2[r][t];
    scl[t] = 1.f / fmaxf(sqrtf(v), 1e-12f);
  }
  __syncthreads();

  {
    int kb2 = t >> 6;    // 0..7 (uniform per wave)
    int lane = t & 63;
    int l4 = lane >> 4;  // k-quarter 0..3
    int pos = lane & 15; // 0..15
    float sc = scl[pos] * 127.f;
    int base = kb2 * 64 + l4 * 16;
    const float4 r0 = *(const float4*)&T[pos][base + 0];
    const float4 r1 = *(const float4*)&T[pos][base + 4];
    const float4 r2 = *(const float4*)&T[pos][base + 8];
    const float4 r3 = *(const float4*)&T[pos][base + 12];
    uint4 u;
    u.x = pk4(r0.x * sc, r0.y * sc, r0.z * sc, r0.w * sc);
    u.y = pk4(r1.x * sc, r1.y * sc, r1.z * sc, r1.w * sc);
    u.z = pk4(r2.x * sc, r2.y * sc, r2.z * sc, r2.w * sc);
    u.w = pk4(r3.x * sc, r3.y * sc, r3.z * sc, r3.w * sc);
    *(uint4*)(out + (size_t)kb2 * 12288 + (size_t)q * 1024 + (size_t)lane * 16) = u;
  }
}

// R17: the half-fixes of R13 and R15, combined properly. R13 had the
// one-tile-ahead reg pipeline but __syncthreads' full vmcnt(0)+lgkmcnt(0)
// drain + reads-then-MFMAs program order convoyed the DS queue (108us).
// R15/R16 had counted waits + raw barrier but made MFMA(kb) depend on
// SAME-phase DSRD(kb) -> 100% exposed DS backlog (109/114us). This round:
//   PHASE(kb): s_waitcnt vmcnt(0) [drains only stage(kb+1), issued a FULL
//              phase ago -> ~free]; s_barrier [publishes tile kb+1; raw: no
//              lgkm drain of my phase-tail ds_reads];
//              STAGE(kb+2 -> slot (kb+2)%3);
//              6x { DSRD pair jt of tile kb+1 ; 6 MFMA of tile kb (regs,
//                   waits on NOTHING) }  -- interleave pinned with
//              sched_group_barrier(VMEM_READ 6; {DS_READ 2, MFMA 6} x6)
//              so the DS queue fills UNDER the MFMA burst, not before it.
// Budgets/CU/phase: DS 96 b128 = 1152cy, MFMA 1469cy, staged VMEM ~1900cy
// -> overlapped phase ~2000-2200cy x 64 phase-instances/CU ~= 55-60us.
// Safety ledger: WAR on slot (kb+2)%3 = tile kb-1: every wave's DSRD(kb-1)
// (issued PHASE(kb-2)) drained via compiler lgkm before its MFMA(kb-1)
// issue in PHASE(kb-1), which precedes its arrival at PHASE(kb)'s barrier;
// STAGE is after that barrier. RAW on tile kb+1: staged PHASE(kb-1),
// writer vmcnt(0) + barrier at PHASE(kb) top. MFMA(kb) operand regs: read
// PHASE(kb-1), compiler-lgkm'd. All ring/reg indices literal (rule #20).
#define GLOAD_LDS16(gp, lp)                                              \
  __builtin_amdgcn_global_load_lds(                                      \
      (const __attribute__((address_space(1))) unsigned int*)(gp),       \
      (__attribute__((address_space(3))) unsigned int*)(lp), 16, 0, 0)

__global__ __launch_bounds__(256, 2) void qaconv_gemm(
    const unsigned char* __restrict__ ws, const float* __restrict__ fcw,
    const float* __restrict__ bnw, const float* __restrict__ bnb,
    const float* __restrict__ bnm, const float* __restrict__ bnv,
    const float* __restrict__ fcb, const float* __restrict__ lw,
    const float* __restrict__ lb, const float* __restrict__ lm,
    const float* __restrict__ lv, float* __restrict__ out) {
  int bid0 = blockIdx.x;
  int bid = ((bid0 & 7) << 9) + (bid0 >> 3);  // XCD-contiguous supertiles
  int sb = bid >> 6, li = bid & 63;           // 8x8 supertiles
  int g = ((sb >> 3) << 3) + (li >> 3);
  int p = ((sb & 7) << 3) + (li & 7);
  const unsigned char* Bsrc = ws + (size_t)g * SLAB;         // galt[g] frags
  const unsigned char* Asrc = ws + (size_t)(GG + p) * SLAB;  // kern[p] frags

  // 3-slot ring; slot = one K-tile: frag f (0..11 = A R0..11, 12..23 = B)
  // at f*1024 + lane*16.  3 x 24 KB = 72 KB -> 2 blocks/CU.
  __shared__ unsigned char sbuf[3][24576];

  int tid = threadIdx.x;
  int lane = tid & 63;
  int wave = tid >> 6;
  int wi = wave >> 1, wj = wave & 1;
  int l15 = lane & 15, l4 = lane >> 4;

  intx4 acc[6][6];
#pragma unroll
  for (int a = 0; a < 6; ++a)
#pragma unroll
    for (int c = 0; c < 6; ++c) acc[a][c] = (intx4){0, 0, 0, 0};

  // staging: wave w owns frags w*6 .. w*6+5  (w<2 -> A rows, w>=2 -> B rows)
  const unsigned char* stgsrc =
      ((wave < 2) ? Asrc : Bsrc) + (size_t)((wave & 1) * 6) * 1024 +
      (size_t)lane * 16;
  int fbase = wave * 6;  // frag index base (uniform per wave)

#define STAGE(KB)                                                         \
  do {                                                                    \
    const unsigned char* s_ = stgsrc + (size_t)(KB)*12288;                \
    _Pragma("unroll") for (int i_ = 0; i_ < 6; ++i_) {                    \
      GLOAD_LDS16(s_ + i_ * 1024, &sbuf[(KB) % 3][(fbase + i_) * 1024]);  \
    }                                                                     \
  } while (0)

  // register double-buffer: rb = tile kb & 1
  intx4 aR[2][6], bR[2][6];

#define DSRD2(KB, RB, J)                                                  \
  do {                                                                    \
    const unsigned char* cb_ = &sbuf[(KB) % 3][lane * 16];                \
    aR[RB][J] = *(const intx4*)(cb_ + (wi * 6 + (J)) * 1024);             \
    bR[RB][J] = *(const intx4*)(cb_ + (12 + wj * 6 + (J)) * 1024);        \
  } while (0)

#define MFMAG(RB, JT)                                                     \
  do {                                                                    \
    intx4 bb = bR[RB][JT];                                                \
    _Pragma("unroll") for (int it_ = 0; it_ < 6; ++it_)                   \
        acc[it_][JT] = __builtin_amdgcn_mfma_i32_16x16x64_i8(             \
            aR[RB][it_], bb, acc[it_][JT], 0, 0, 0);                      \
  } while (0)

#define SGB __builtin_amdgcn_sched_group_barrier

#define PHASE(KB)                                                         \
  do {                                                                    \
    asm volatile("s_waitcnt vmcnt(0)" ::: "memory");                      \
    __builtin_amdgcn_s_barrier();                                         \
    if ((KB) + 2 <= 7) STAGE((KB) + 2);                                   \
    __builtin_amdgcn_s_setprio(1);                                        \
    _Pragma("unroll") for (int jt_ = 0; jt_ < 6; ++jt_) {                 \
      if ((KB) + 1 <= 7) DSRD2((KB) + 1, ((KB) + 1) & 1, jt_);            \
      MFMAG((KB)&1, jt_);                                                 \
    }                                                                     \
    __builtin_amdgcn_s_setprio(0);                                        \
    if ((KB) + 2 <= 7) SGB(0x20, 6, 0); /* 6 global_load_lds first */     \
    _Pragma("unroll") for (int jt_ = 0; jt_ < 6; ++jt_) {                 \
      if ((KB) + 1 <= 7) SGB(0x100, 2, 0); /* 2 ds_read */                \
      SGB(0x8, 6, 0);                      /* 6 MFMA */                   \
    }                                                                     \
  } while (0)

  // prologue: stage tiles 0,1; publish tile 0; read it to regs
  STAGE(0);
  STAGE(1);
  asm volatile("s_waitcnt vmcnt(6)" ::: "memory");  // stage(0) landed
  __builtin_amdgcn_s_barrier();
#pragma unroll
  for (int j = 0; j < 6; ++j) DSRD2(0, 0, j);

  PHASE(0);
  PHASE(1);
  PHASE(2);
  PHASE(3);
  PHASE(4);
  PHASE(5);
  PHASE(6);
  PHASE(7);

#undef STAGE
#undef DSRD2
#undef MFMAG
#undef PHASE
#undef SGB

  __syncthreads();  // full drain; safe to alias sbuf for epilogue

  // epilogue scratch aliases the stage buffer
  float (*colpart)[HW] = (float (*)[HW]) & sbuf[0][0];      // [2][192]
  float (*rowpart)[HW] = (float (*)[HW]) & sbuf[0][1536];   // [2][192]
  float (*redbuf)[2] = (float (*)[2]) & sbuf[0][3072];      // [4][2]

  // ---- epilogue: dual max-pool in int32 ----
  // C/D layout: i = wi*96 + it*16 + l4*4 + r ; j = wj*96 + jt*16 + l15
  const float inv = 1.f / 16129.f;  // 1/127^2
  int cm[6];
  int rm[6][4];
#pragma unroll
  for (int jt = 0; jt < 6; ++jt) cm[jt] = -2147483647;
#pragma unroll
  for (int it = 0; it < 6; ++it)
#pragma unroll
    for (int r = 0; r < 4; ++r) rm[it][r] = -2147483647;
#pragma unroll
  for (int it = 0; it < 6; ++it)
#pragma unroll
    for (int jt = 0; jt < 6; ++jt)
#pragma unroll
      for (int r = 0; r < 4; ++r) {
        int v = acc[it][jt][r];
        cm[jt] = max(cm[jt], v);
        rm[it][r] = max(rm[it][r], v);
      }

#pragma unroll
  for (int jt = 0; jt < 6; ++jt) {
    int v = cm[jt];
    v = max(v, __shfl_xor(v, 16, 64));
    v = max(v, __shfl_xor(v, 32, 64));
    if (lane < 16) colpart[wi][wj * 96 + jt * 16 + lane] = (float)v * inv;
  }
#pragma unroll
  for (int it = 0; it < 6; ++it)
#pragma unroll
    for (int r = 0; r < 4; ++r) {
      int v = rm[it][r];
      v = max(v, __shfl_xor(v, 1, 64));
      v = max(v, __shfl_xor(v, 2, 64));
      v = max(v, __shfl_xor(v, 4, 64));
      v = max(v, __shfl_xor(v, 8, 64));
      if (l15 == 0) rowpart[wj][wi * 96 + it * 16 + l4 * 4 + r] = (float)v * inv;
    }
  __syncthreads();

  // ---- fused BN -> fc -> lbn -> sigmoid ----
  float part = 0.f, wpart = 0.f;
  if (tid < HW) {
    float cmax = fmaxf(colpart[0][tid], colpart[1][tid]);  // score[j]
    float rmax = fmaxf(rowpart[0][tid], rowpart[1][tid]);  // score[192+i]
    float w1 = fcw[tid], w2 = fcw[HW + tid];
    part = cmax * w1 + rmax * w2;
    wpart = w1 + w2;
  }
#pragma unroll
  for (int off = 32; off > 0; off >>= 1) {
    part += __shfl_down(part, off, 64);
    wpart += __shfl_down(wpart, off, 64);
  }
  if (lane == 0) { redbuf[wave][0] = part; redbuf[wave][1] = wpart; }
  __syncthreads();
  if (tid == 0) {
    float s = redbuf[0][0] + redbuf[1][0] + redbuf[2][0] + redbuf[3][0];
    float wsum = redbuf[0][1] + redbuf[1][1] + redbuf[2][1] + redbuf[3][1];
    float bnA = bnw[0] * rsqrtf(bnv[0] + 1e-5f);
    float bnB = bnb[0] - bnm[0] * bnA;
    float sc = bnA * s + bnB * wsum + fcb[0];
    float lA = lw[0] * rsqrtf(lv[0] + 1e-5f);
    sc = (sc - lm[0]) * lA + lb[0];
    out[g * PP + p] = 1.f / (1.f + __expf(-sc * 0.1f));
  }
}

extern "C" void kernel_launch(void* const* d_in, const int* in_sizes, int n_in,
                              void* d_out, int out_size, void* d_ws, size_t ws_size,
                              hipStream_t stream) {
  const float* gal  = (const float*)d_in[0];
  const float* prob = (const float*)d_in[1];
  const float* bnw  = (const float*)d_in[2];
  const float* bnb  = (const float*)d_in[3];
  const float* bnm  = (const float*)d_in[4];
  const float* bnv  = (const float*)d_in[5];
  const float* fcw  = (const float*)d_in[6];
  const float* fcb  = (const float*)d_in[7];
  const float* lw   = (const float*)d_in[8];
  const float* lb   = (const float*)d_in[9];
  const float* lm   = (const float*)d_in[10];
  const float* lv   = (const float*)d_in[11];
  unsigned char* ws = (unsigned char*)d_ws;
  float* out = (float*)d_out;

  hipLaunchKernelGGL(norm_kernel, dim3(1536), dim3(512), 0, stream, gal, prob, ws);
  hipLaunchKernelGGL(qaconv_gemm, dim3(GG * PP), dim3(256), 0, stream, ws, fcw,
                     bnw, bnb, bnm, bnv, fcb, lw, lb, lm, lv, out);
}

// Round 8
// 195.565 us; speedup vs baseline: 1.2415x; 1.0052x over previous
//
#include <hip/hip_runtime.h>

#define HW 192
#define DD 512
#define GG 64
#define PP 64
#define SLAB 98304  // 192*512 i8 bytes per slab

typedef __attribute__((ext_vector_type(4))) int intx4;

__device__ __forceinline__ unsigned int pk4(float a, float b, float c, float d) {
  int qa = (int)rintf(a), qb = (int)rintf(b), qc = (int)rintf(c), qd = (int)rintf(d);
  return (unsigned)(qa & 255) | ((unsigned)(qb & 255) << 8) |
         ((unsigned)(qc & 255) << 16) | ((unsigned)(qd & 255) << 24);
}

// R18 norm rewrite. The 8-round-stable residual (total - gemm ~= 93us) is
// either this kernel or harness floor; a roofline rewrite splits it
// decisively and is the win if it's the kernel. Old structure: 1536 blocks,
// 43KB LDS transpose, 16x64B-segment strided loads. New: 384 blocks
// (slab s, pos-third h: 64 positions), 256 thr, 1.3KB LDS:
//  phase1: wave w owns channels w*128..+127; lane owns pos h*64+lane;
//          in[c*192 + h*64 + lane] = 256B coalesced wave-loads; ssq in reg.
//  reduce: ssqA[4][64] -> sc127[pos] = 127/max(sqrt,1e-12)  (== old scl*127)
//  phase2: thread (lpos=t&15, l4=(t>>4)&3, qloc=t>>6) x kb2(8): reads 16
//          chans (c0=kb2*64+l4*16) of its pos from L2-hot lines, pk4-packs
//          one uint4, stores ws[s] + kb2*12288 + q*1024 + (l4*16+lpos)*16
//          -> per wave a contiguous 1KB store. Layout byte-identical to the
//          R0 gemm's fragment order (pos=q*16+lpos, chan=kb2*64+l4*16+j).
__global__ __launch_bounds__(256, 4) void norm_kernel(
    const float* __restrict__ gal, const float* __restrict__ prob,
    unsigned char* __restrict__ ws) {
  int b = blockIdx.x;  // 0..383
  int s = b / 3;       // slab 0..127
  int h = b - s * 3;   // pos-third 0..2
  const float* in = (s < GG) ? (gal + (size_t)s * DD * HW)
                             : (prob + (size_t)(s - GG) * DD * HW);
  unsigned char* out = ws + (size_t)s * SLAB;
  int t = threadIdx.x;
  int lane = t & 63;
  int wave = t >> 6;  // 0..3

  __shared__ float ssqA[4][64];
  __shared__ float sc127[64];

  // phase 1: per-position sum of squares (channel-split across waves)
  {
    const float* base = in + (size_t)(wave * 128) * HW + h * 64 + lane;
    float ssq = 0.f;
#pragma unroll 8
    for (int k = 0; k < 128; ++k) {
      float v = base[(size_t)k * HW];
      ssq += v * v;
    }
    ssqA[wave][lane] = ssq;
  }
  __syncthreads();
  if (t < 64) {
    float v = ssqA[0][t] + ssqA[1][t] + ssqA[2][t] + ssqA[3][t];
    sc127[t] = 127.f / fmaxf(sqrtf(v), 1e-12f);
  }
  __syncthreads();

  // phase 2: quantize + fragment-layout store
  {
    int lpos = t & 15, l4 = (t >> 4) & 3, qloc = t >> 6;
    int posl = qloc * 16 + lpos;  // 0..63 local position
    int q = h * 4 + qloc;         // global 16-pos group 0..11
    float sc = sc127[posl];
    const float* pbase = in + (size_t)h * 64 + posl;
    uint4* o = (uint4*)out;
#pragma unroll
    for (int kb2 = 0; kb2 < 8; ++kb2) {
      int c0 = kb2 * 64 + l4 * 16;
      const float* cp = pbase + (size_t)c0 * HW;
      float v[16];
#pragma unroll
      for (int j = 0; j < 16; ++j) v[j] = cp[(size_t)j * HW] * sc;
      uint4 u;
      u.x = pk4(v[0], v[1], v[2], v[3]);
      u.y = pk4(v[4], v[5], v[6], v[7]);
      u.z = pk4(v[8], v[9], v[10], v[11]);
      u.w = pk4(v[12], v[13], v[14], v[15]);
      o[kb2 * 768 + q * 64 + l4 * 16 + lpos] = u;
    }
  }
}

// gemm: byte-exact revert to the session-best R0 kernel (97.7us measured).
// One block per (g,p), int8 via mfma_i32_16x16x64_i8. No LDS / no barriers
// in K-loop, 12 x 1KB contiguous wave-loads per kb2, register
// double-buffered. Epilogue: max-pool in int32 (monotone), one float
// convert * (1/127^2) at the end.
__global__ __launch_bounds__(256, 2) void qaconv_gemm(
    const unsigned char* __restrict__ ws, const float* __restrict__ fcw,
    const float* __restrict__ bnw, const float* __restrict__ bnb,
    const float* __restrict__ bnm, const float* __restrict__ bnv,
    const float* __restrict__ fcb, const float* __restrict__ lw,
    const float* __restrict__ lb, const float* __restrict__ lm,
    const float* __restrict__ lv, float* __restrict__ out) {
  int bid = blockIdx.x;
  int sb = bid >> 6, li = bid & 63;  // 8x8 supertiles for L2 locality
  int g = ((sb >> 3) << 3) + (li >> 3);
  int p = ((sb & 7) << 3) + (li & 7);
  const unsigned char* Bsrc = ws + (size_t)g * SLAB;         // galt[g] frags
  const unsigned char* Asrc = ws + (size_t)(GG + p) * SLAB;  // kern[p] frags

  __shared__ float colpart[2][HW];
  __shared__ float rowpart[2][HW];
  __shared__ float redbuf[4][2];

  int tid = threadIdx.x;
  int lane = tid & 63;
  int wave = tid >> 6;
  int wi = wave >> 1, wj = wave & 1;
  int l15 = lane & 15, l4 = lane >> 4;

  intx4 acc[6][6];
#pragma unroll
  for (int a = 0; a < 6; ++a)
#pragma unroll
    for (int c = 0; c < 6; ++c) acc[a][c] = (intx4){0, 0, 0, 0};

  // frag (it) lives at R = wi*6+it (A) / wj*6+jt (B)
  const unsigned char* aP = Asrc + (size_t)(wi * 6) * 1024 + (size_t)lane * 16;
  const unsigned char* bP = Bsrc + (size_t)(wj * 6) * 1024 + (size_t)lane * 16;

#define LOADF(AD, BD, KB)                                                 \
  do {                                                                    \
    _Pragma("unroll") for (int it_ = 0; it_ < 6; ++it_) {                 \
      AD[it_] = *(const intx4*)(aP + (size_t)(KB)*12288 + it_ * 1024);    \
      BD[it_] = *(const intx4*)(bP + (size_t)(KB)*12288 + it_ * 1024);    \
    }                                                                     \
  } while (0)

#define MFMAB(AD, BD)                                                     \
  do {                                                                    \
    _Pragma("unroll") for (int jt_ = 0; jt_ < 6; ++jt_) {                 \
      intx4 bb = BD[jt_];                                                 \
      _Pragma("unroll") for (int it_ = 0; it_ < 6; ++it_)                 \
          acc[it_][jt_] = __builtin_amdgcn_mfma_i32_16x16x64_i8(          \
              AD[it_], bb, acc[it_][jt_], 0, 0, 0);                       \
    }                                                                     \
  } while (0)

  intx4 aC[6], bC[6], aN[6], bN[6];
  LOADF(aC, bC, 0);
#pragma unroll 1
  for (int kb2 = 0; kb2 < 8; kb2 += 2) {
    LOADF(aN, bN, kb2 + 1);
    MFMAB(aC, bC);
    if (kb2 < 6) LOADF(aC, bC, kb2 + 2);
    MFMAB(aN, bN);
  }
#undef LOADF
#undef MFMAB

  // ---- epilogue: dual max-pool in int32 ----
  // C/D layout: i = wi*96 + it*16 + l4*4 + r ; j = wj*96 + jt*16 + l15
  const float inv = 1.f / 16129.f;  // 1/127^2
  int cm[6];
  int rm[6][4];
#pragma unroll
  for (int jt = 0; jt < 6; ++jt) cm[jt] = -2147483647;
#pragma unroll
  for (int it = 0; it < 6; ++it)
#pragma unroll
    for (int r = 0; r < 4; ++r) rm[it][r] = -2147483647;
#pragma unroll
  for (int it = 0; it < 6; ++it)
#pragma unroll
    for (int jt = 0; jt < 6; ++jt)
#pragma unroll
      for (int r = 0; r < 4; ++r) {
        int v = acc[it][jt][r];
        cm[jt] = max(cm[jt], v);
        rm[it][r] = max(rm[it][r], v);
      }

#pragma unroll
  for (int jt = 0; jt < 6; ++jt) {
    int v = cm[jt];
    v = max(v, __shfl_xor(v, 16, 64));
    v = max(v, __shfl_xor(v, 32, 64));
    if (lane < 16) colpart[wi][wj * 96 + jt * 16 + lane] = (float)v * inv;
  }
#pragma unroll
  for (int it = 0; it < 6; ++it)
#pragma unroll
    for (int r = 0; r < 4; ++r) {
      int v = rm[it][r];
      v = max(v, __shfl_xor(v, 1, 64));
      v = max(v, __shfl_xor(v, 2, 64));
      v = max(v, __shfl_xor(v, 4, 64));
      v = max(v, __shfl_xor(v, 8, 64));
      if (l15 == 0) rowpart[wj][wi * 96 + it * 16 + l4 * 4 + r] = (float)v * inv;
    }
  __syncthreads();

  // ---- fused BN -> fc -> lbn -> sigmoid ----
  float part = 0.f, wpart = 0.f;
  if (tid < HW) {
    float cmax = fmaxf(colpart[0][tid], colpart[1][tid]);  // score[j]
    float rmax = fmaxf(rowpart[0][tid], rowpart[1][tid]);  // score[192+i]
    float w1 = fcw[tid], w2 = fcw[HW + tid];
    part = cmax * w1 + rmax * w2;
    wpart = w1 + w2;
  }
#pragma unroll
  for (int off = 32; off > 0; off >>= 1) {
    part += __shfl_down(part, off, 64);
    wpart += __shfl_down(wpart, off, 64);
  }
  if (lane == 0) { redbuf[wave][0] = part; redbuf[wave][1] = wpart; }
  __syncthreads();
  if (tid == 0) {
    float s = redbuf[0][0] + redbuf[1][0] + redbuf[2][0] + redbuf[3][0];
    float wsum = redbuf[0][1] + redbuf[1][1] + redbuf[2][1] + redbuf[3][1];
    float bnA = bnw[0] * rsqrtf(bnv[0] + 1e-5f);
    float bnB = bnb[0] - bnm[0] * bnA;
    float sc = bnA * s + bnB * wsum + fcb[0];
    float lA = lw[0] * rsqrtf(lv[0] + 1e-5f);
    sc = (sc - lm[0]) * lA + lb[0];
    out[g * PP + p] = 1.f / (1.f + __expf(-sc * 0.1f));
  }
}

extern "C" void kernel_launch(void* const* d_in, const int* in_sizes, int n_in,
                              void* d_out, int out_size, void* d_ws, size_t ws_size,
                              hipStream_t stream) {
  const float* gal  = (const float*)d_in[0];
  const float* prob = (const float*)d_in[1];
  const float* bnw  = (const float*)d_in[2];
  const float* bnb  = (const float*)d_in[3];
  const float* bnm  = (const float*)d_in[4];
  const float* bnv  = (const float*)d_in[5];
  const float* fcw  = (const float*)d_in[6];
  const float* fcb  = (const float*)d_in[7];
  const float* lw   = (const float*)d_in[8];
  const float* lb   = (const float*)d_in[9];
  const float* lm   = (const float*)d_in[10];
  const float* lv   = (const float*)d_in[11];
  unsigned char* ws = (unsigned char*)d_ws;
  float* out = (float*)d_out;

  hipLaunchKernelGGL(norm_kernel, dim3(384), dim3(256), 0, stream, gal, prob, ws);
  hipLaunchKernelGGL(qaconv_gemm, dim3(GG * PP), dim3(256), 0, stream, ws, fcw,
                     bnw, bnb, bnm, bnv, fcb, lw, lb, lm, lv, out);
}